// Round 2
// baseline (12774.171 us; speedup 1.0000x reference)
//
#include <hip/hip_runtime.h>
#include <math.h>

#define NB   8          // batch rows per block
#define TT   400
#define HH   128
#define CC   96
#define DD   4096
#define GJ   512        // gate columns: r-comb(128) z-comb(128) i_n(128) h_n(128)
#define THRV (1.0f - 1e-5f)

__device__ __forceinline__ float sigm(float v) { return 1.0f / (1.0f + expf(-v)); }

__global__ __launch_bounds__(1024, 4)
void gru_title(const float* __restrict__ img,
               const float* __restrict__ l1w,
               const float* __restrict__ l1b,
               const float* __restrict__ wih,
               const float* __restrict__ whh,
               const float* __restrict__ bih,
               const float* __restrict__ bhh,
               const float* __restrict__ l2w,
               const float* __restrict__ l2b,
               float* __restrict__ out,
               float* __restrict__ lens)
{
    __shared__ alignas(16) float xs[NB][HH];   // h_t (== GRU input for t>=1)
    __shared__ alignas(16) float xl[NB][HH];   // leaky(h_t)
    __shared__ alignas(16) float gs[NB][GJ];   // gate pre-activations
    __shared__ alignas(16) float chs[NB][CC];  // chars
    __shared__ int sh_done[NB];
    __shared__ int sh_len[NB];

    const int tid = threadIdx.x;
    const int b0  = blockIdx.x * NB;

    const int j  = tid >> 1;    // gate column 0..511
    const int h  = tid & 1;     // K-half
    const int hb = h * 64;      // k base for this half

    if (tid < NB) { sh_done[tid] = 0; sh_len[tid] = TT; }

    // ---- per-thread combined gate weights: 64 floats (half a column) ----
    float wreg[64];
    float bj;
    if (j < 256) {              // r,z: w_ih + w_hh combined (input == hidden for t>=1)
        const float4* p0 = (const float4*)(wih + (size_t)j * HH + hb);
        const float4* p1 = (const float4*)(whh + (size_t)j * HH + hb);
        #pragma unroll
        for (int k = 0; k < 16; ++k) {
            float4 a = p0[k], b = p1[k];
            wreg[4*k+0] = a.x + b.x; wreg[4*k+1] = a.y + b.y;
            wreg[4*k+2] = a.z + b.z; wreg[4*k+3] = a.w + b.w;
        }
        bj = (h == 0) ? (bih[j] + bhh[j]) : 0.f;
    } else if (j < 384) {       // i_n
        const float4* p0 = (const float4*)(wih + (size_t)j * HH + hb);
        #pragma unroll
        for (int k = 0; k < 16; ++k) {
            float4 a = p0[k];
            wreg[4*k+0] = a.x; wreg[4*k+1] = a.y; wreg[4*k+2] = a.z; wreg[4*k+3] = a.w;
        }
        bj = (h == 0) ? bih[j] : 0.f;
    } else {                    // h_n
        const float4* p0 = (const float4*)(whh + (size_t)(j - 128) * HH + hb);
        #pragma unroll
        for (int k = 0; k < 16; ++k) {
            float4 a = p0[k];
            wreg[4*k+0] = a.x; wreg[4*k+1] = a.y; wreg[4*k+2] = a.z; wreg[4*k+3] = a.w;
        }
        bj = (h == 0) ? bhh[j - 128] : 0.f;
    }

    // ---- prologue: x0 = leaky(img @ l1w.T + l1b); thread = (row m, col c) ----
    {
        const int m = tid >> 7;          // 0..7
        const int c = tid & 127;
        const float4* xp = (const float4*)(img + (size_t)(b0 + m) * DD);
        const float4* wp = (const float4*)(l1w + (size_t)c * DD);
        float a0 = 0.f, a1 = 0.f;
        #pragma unroll 4
        for (int k = 0; k < DD/4; k += 2) {
            float4 w0 = wp[k], w1 = wp[k+1];
            float4 u0 = xp[k], u1 = xp[k+1];
            a0 += w0.x*u0.x + w0.y*u0.y + w0.z*u0.z + w0.w*u0.w;
            a1 += w1.x*u1.x + w1.y*u1.y + w1.z*u1.z + w1.w*u1.w;
        }
        float hv = a0 + a1 + l1b[c];
        xs[m][c] = (hv >= 0.f) ? hv : 0.01f * hv;
    }
    __syncthreads();

    // ---- l2w fragment: thread = (col cc_, K-eighth kq) holds 16 floats ----
    const int cc_ = tid >> 3;    // 0..127 (>=96 idle in chars phase)
    const int kq  = tid & 7;
    float l2f[16];
    float cb = 0.f;
    if (cc_ < CC) {
        const float4* p = (const float4*)(l2w + (size_t)cc_ * HH + kq * 16);
        #pragma unroll
        for (int k = 0; k < 4; ++k) {
            float4 a = p[k];
            l2f[4*k+0] = a.x; l2f[4*k+1] = a.y; l2f[4*k+2] = a.z; l2f[4*k+3] = a.w;
        }
        if (kq == 0) cb = l2b[cc_];
    }

    const int wav  = tid >> 6;
    const int lane = tid & 63;

    for (int t = 0; t < TT; ++t) {
        // ---------- gates: acc[m] = x[m] . w[j][hb..hb+64) ----------
        {
            float acc[NB];
            #pragma unroll
            for (int m = 0; m < NB; ++m) acc[m] = 0.f;

            if (t == 0) {
                // h_prev = 0: r/z/i_n use w_ih only; h_n column contributes bias only
                if (j < 384) {
                    const float4* p0 = (const float4*)(wih + (size_t)j * HH + hb);
                    #pragma unroll
                    for (int k = 0; k < 16; ++k) {
                        float4 w = p0[k];
                        #pragma unroll
                        for (int m = 0; m < NB; ++m) {
                            float4 x = *(const float4*)&xs[m][hb + 4*k];
                            acc[m] += w.x*x.x + w.y*x.y + w.z*x.z + w.w*x.w;
                        }
                    }
                }
            } else {
                const float4* wv = (const float4*)wreg;
                #pragma unroll
                for (int k = 0; k < 16; ++k) {
                    float4 w = wv[k];
                    #pragma unroll
                    for (int m = 0; m < NB; ++m) {
                        float4 x = *(const float4*)&xs[m][hb + 4*k];
                        acc[m] += w.x*x.x + w.y*x.y + w.z*x.z + w.w*x.w;
                    }
                }
            }
            // combine K-halves: partner lane is tid^1 (same wave)
            #pragma unroll
            for (int m = 0; m < NB; ++m) {
                float s = acc[m] + __shfl_xor(acc[m], 1, 64);
                if (h == 0) gs[m][j] = s + bj;
            }
        }
        __syncthreads();

        // ---------- gate nonlinearity + state update: thread = (m, i) ----------
        {
            const int m = tid >> 7;
            const int i = tid & 127;
            float gr = gs[m][i];
            float gz = gs[m][HH + i];
            float gi = gs[m][2*HH + i];
            float gh = gs[m][3*HH + i];
            float r  = sigm(gr);
            float z  = sigm(gz);
            float n  = tanhf(gi + r * gh);
            float hp = (t == 0) ? 0.f : xs[m][i];
            float hv = (1.f - z) * n + z * hp;
            xs[m][i] = hv;
            xl[m][i] = (hv >= 0.f) ? hv : 0.01f * hv;
        }
        __syncthreads();

        // ---------- chars = leaky(h) @ l2w.T + l2b, K split 8 ways ----------
        if (cc_ < CC) {
            float a[NB];
            #pragma unroll
            for (int m = 0; m < NB; ++m) a[m] = cb;
            const int kb = kq * 16;
            #pragma unroll
            for (int k4 = 0; k4 < 4; ++k4) {
                #pragma unroll
                for (int m = 0; m < NB; ++m) {
                    float4 x = *(const float4*)&xl[m][kb + 4*k4];
                    a[m] += l2f[4*k4+0]*x.x + l2f[4*k4+1]*x.y
                          + l2f[4*k4+2]*x.z + l2f[4*k4+3]*x.w;
                }
            }
            // tree-sum the 8 K-slices (lanes kq within a col group)
            #pragma unroll
            for (int m = 0; m < NB; ++m) {
                a[m] += __shfl_xor(a[m], 1, 64);
                a[m] += __shfl_xor(a[m], 2, 64);
                a[m] += __shfl_xor(a[m], 4, 64);
            }
            if (kq == 0) {
                #pragma unroll
                for (int m = 0; m < NB; ++m) chs[m][cc_] = a[m];
            }
        }
        __syncthreads();

        // ---------- max / divide / threshold / scatter / len detect ----------
        if (wav < NB) {
            float v0 = chs[wav][lane];
            float v1 = (lane < 32) ? chs[wav][64 + lane] : -INFINITY;
            float mx = fmaxf(v0, v1);
            #pragma unroll
            for (int s = 32; s > 0; s >>= 1) mx = fmaxf(mx, __shfl_xor(mx, s, 64));
            float q0 = v0 / mx;
            size_t base = ((size_t)(b0 + wav) * TT + t) * CC;
            if (q0 > THRV) out[base + lane] = q0;
            if (lane < 32) {
                float q1 = v1 / mx;
                if (q1 > THRV) out[base + 64 + lane] = q1;
            }
            float q52 = __shfl(q0, 52, 64);
            if (lane == 0 && q52 == 1.0f && sh_done[wav] == 0) {
                sh_done[wav] = 1;
                sh_len[wav]  = t + 1;
            }
        }
        __syncthreads();

        // uniform early exit: titles beyond this point are free (threshold >= 1.0),
        // lens for all rows in this block are already determined.
        if (sh_done[0] & sh_done[1] & sh_done[2] & sh_done[3] &
            sh_done[4] & sh_done[5] & sh_done[6] & sh_done[7]) break;
    }

    if (tid < NB) lens[b0 + tid] = (float)sh_len[tid];
}

extern "C" void kernel_launch(void* const* d_in, const int* in_sizes, int n_in,
                              void* d_out, int out_size, void* d_ws, size_t ws_size,
                              hipStream_t stream)
{
    const float* img = (const float*)d_in[0];
    const float* l1w = (const float*)d_in[1];
    const float* l1b = (const float*)d_in[2];
    const float* wih = (const float*)d_in[3];
    const float* whh = (const float*)d_in[4];
    const float* bih = (const float*)d_in[5];
    const float* bhh = (const float*)d_in[6];
    const float* l2w = (const float*)d_in[7];
    const float* l2b = (const float*)d_in[8];

    float* out  = (float*)d_out;
    float* lens = out + (size_t)2048 * TT * CC;

    // titles are ~99% zeros; kernel scatters only the surviving entries.
    hipMemsetAsync(d_out, 0, (size_t)out_size * sizeof(float), stream);

    gru_title<<<dim3(2048 / NB), dim3(1024), 0, stream>>>(
        img, l1w, l1b, wih, whh, bih, bhh, l2w, l2b, out, lens);
}

// Round 3
// 4422.966 us; speedup vs baseline: 2.8881x; 2.8881x over previous
//
#include <hip/hip_runtime.h>
#include <math.h>

#define NB   8          // rows per block
#define TT   400
#define HH   128
#define CC   96
#define DD   4096
#define GJ   512
#define THRV (1.0f - 1e-5f)

__device__ __forceinline__ float sigm(float v) { return 1.0f / (1.0f + expf(-v)); }

__global__ __launch_bounds__(512, 2)
void gru_title(const float* __restrict__ img,
               const float* __restrict__ l1w,
               const float* __restrict__ l1b,
               const float* __restrict__ wih,
               const float* __restrict__ whh,
               const float* __restrict__ bih,
               const float* __restrict__ bhh,
               const float* __restrict__ l2w,
               const float* __restrict__ l2b,
               float* __restrict__ out,
               float* __restrict__ lens)
{
    __shared__ alignas(16) float xs[NB][HH];   // h_t (input & hidden; = ht0 at t=0)
    __shared__ alignas(16) float xl[NB][HH];   // leaky(h_t)
    __shared__ alignas(16) float gs[NB][GJ];   // raw gate pre-activations
    __shared__ alignas(16) float chs[NB][CC];  // chars
    __shared__ int sh_stable;                  // block-wide bitwise fixed-point flag

    const int tid = threadIdx.x;
    const int b0  = blockIdx.x * NB;

    // ---- combined gate weights, register-resident (rows: r-comb, z-comb, i_n, h_n) ----
    float wreg[HH];
    float bj;
    if (tid < 256) {
        const float4* p0 = (const float4*)(wih + (size_t)tid * HH);
        const float4* p1 = (const float4*)(whh + (size_t)tid * HH);
        #pragma unroll
        for (int k = 0; k < HH/4; ++k) {
            float4 a = p0[k], b = p1[k];
            wreg[4*k+0] = a.x + b.x; wreg[4*k+1] = a.y + b.y;
            wreg[4*k+2] = a.z + b.z; wreg[4*k+3] = a.w + b.w;
        }
        bj = bih[tid] + bhh[tid];
    } else if (tid < 384) {
        const float4* p0 = (const float4*)(wih + (size_t)tid * HH);
        #pragma unroll
        for (int k = 0; k < HH/4; ++k) {
            float4 a = p0[k];
            wreg[4*k+0] = a.x; wreg[4*k+1] = a.y; wreg[4*k+2] = a.z; wreg[4*k+3] = a.w;
        }
        bj = bih[tid];
    } else {
        const float4* p0 = (const float4*)(whh + (size_t)(tid - 128) * HH);
        #pragma unroll
        for (int k = 0; k < HH/4; ++k) {
            float4 a = p0[k];
            wreg[4*k+0] = a.x; wreg[4*k+1] = a.y; wreg[4*k+2] = a.z; wreg[4*k+3] = a.w;
        }
        bj = bhh[tid - 128];
    }

    // chars-phase constants (threads 0..191 use them)
    const int    cc_   = tid % CC;
    const int    cm0   = (tid / CC) * 4;
    const float  cbias = l2b[cc_];
    const float4* l2row = (const float4*)(l2w + (size_t)cc_ * HH);

    // ---- prologue: x0 = leaky(img @ l1w.T + l1b), 2 rows per thread ----
    {
        const int c  = tid & 127;
        const int mh = tid >> 7;            // 0..3
        const int r0 = 2*mh, r1 = r0 + 1;
        const float4* xp0 = (const float4*)(img + (size_t)(b0 + r0) * DD);
        const float4* xp1 = (const float4*)(img + (size_t)(b0 + r1) * DD);
        const float4* wp  = (const float4*)(l1w + (size_t)c * DD);
        float a0 = 0.f, b0v = 0.f, a1 = 0.f, b1v = 0.f;
        #pragma unroll 4
        for (int k = 0; k < DD/4; k += 2) {
            float4 w0 = wp[k],  w1 = wp[k+1];
            float4 u0 = xp0[k], u1 = xp0[k+1];
            float4 v0 = xp1[k], v1 = xp1[k+1];
            a0  += w0.x*u0.x + w0.y*u0.y + w0.z*u0.z + w0.w*u0.w;
            b0v += w1.x*u1.x + w1.y*u1.y + w1.z*u1.z + w1.w*u1.w;
            a1  += w0.x*v0.x + w0.y*v0.y + w0.z*v0.z + w0.w*v0.w;
            b1v += w1.x*v1.x + w1.y*v1.y + w1.z*v1.z + w1.w*v1.w;
        }
        float h0 = a0 + b0v + l1b[c];
        float h1 = a1 + b1v + l1b[c];
        xs[r0][c] = (h0 >= 0.f) ? h0 : 0.01f*h0;
        xs[r1][c] = (h1 >= 0.f) ? h1 : 0.01f*h1;
    }
    __syncthreads();

    const int wav  = tid >> 6;   // wave w handles row w in phase 4
    const int lane = tid & 63;
    int  len   = TT;
    bool found = false;
    int  tex   = TT;             // step at which bitwise fixed point was detected

    for (int t = 0; t < TT; ++t) {
        // ---------- gates GEMM: g[m][j] ----------
        if (tid == 0) sh_stable = 1;   // reset; separated from readers by barriers
        if (t == 0) {
            // h_prev = 0: r/z/i_n from w_ih only; h_n block = b_hh_n (bias only)
            float acc[NB];
            #pragma unroll
            for (int m = 0; m < NB; ++m) acc[m] = bj;
            if (tid < 384) {
                const float4* wp = (const float4*)(wih + (size_t)tid * HH);
                #pragma unroll
                for (int k = 0; k < HH/4; ++k) {
                    float4 w = wp[k];
                    #pragma unroll
                    for (int m = 0; m < NB; ++m) {
                        float4 x = *(const float4*)&xs[m][4*k];
                        acc[m] += w.x*x.x + w.y*x.y + w.z*x.z + w.w*x.w;
                    }
                }
            }
            #pragma unroll
            for (int m = 0; m < NB; ++m) gs[m][tid] = acc[m];
        } else {
            #pragma unroll
            for (int m = 0; m < NB; ++m) {
                float s0 = bj, s1 = 0.f;
                #pragma unroll
                for (int k = 0; k < HH/8; ++k) {
                    float4 x0 = *(const float4*)&xs[m][8*k];
                    float4 x1 = *(const float4*)&xs[m][8*k+4];
                    s0 += x0.x*wreg[8*k+0] + x0.y*wreg[8*k+1] + x0.z*wreg[8*k+2] + x0.w*wreg[8*k+3];
                    s1 += x1.x*wreg[8*k+4] + x1.y*wreg[8*k+5] + x1.z*wreg[8*k+6] + x1.w*wreg[8*k+7];
                }
                gs[m][tid] = s0 + s1;
            }
        }
        __syncthreads();

        // ---------- gate nonlinearity + state update (+ fixed-point compare) ----------
        {
            const int i  = tid & 127;
            const int mh = tid >> 7;
            bool changed = false;
            #pragma unroll
            for (int g = 0; g < 2; ++g) {
                const int m = mh + 4*g;
                float r  = sigm(gs[m][i]);
                float z  = sigm(gs[m][HH + i]);
                float n  = tanhf(gs[m][2*HH + i] + r * gs[m][3*HH + i]);
                float hp = (t == 0) ? 0.f : xs[m][i];
                float h  = (1.f - z) * n + z * hp;
                changed |= (__float_as_uint(h) != __float_as_uint(hp));
                xs[m][i] = h;
                xl[m][i] = (h >= 0.f) ? h : 0.01f * h;
            }
            if (changed) sh_stable = 0;   // benign multi-writer race
        }
        __syncthreads();

        // bitwise fixed point: every future chars vector is identical to the one
        // already in chs (from step t-1). Replicate in the epilogue. Exact.
        if (t > 0 && sh_stable) { tex = t; break; }

        // ---------- chars = leaky(h) @ l2w.T + l2b (threads 0..191, 4 rows each) ----------
        if (tid < 192) {
            float a[4];
            #pragma unroll
            for (int mi = 0; mi < 4; ++mi) a[mi] = cbias;
            #pragma unroll
            for (int k = 0; k < HH/4; ++k) {
                float4 w = l2row[k];
                #pragma unroll
                for (int mi = 0; mi < 4; ++mi) {
                    float4 x = *(const float4*)&xl[cm0 + mi][4*k];
                    a[mi] += w.x*x.x + w.y*x.y + w.z*x.z + w.w*x.w;
                }
            }
            #pragma unroll
            for (int mi = 0; mi < 4; ++mi) chs[cm0 + mi][cc_] = a[mi];
        }
        __syncthreads();

        // ---------- max / divide / threshold / sparse scatter / lens ----------
        {
            float v0 = chs[wav][lane];
            float v1 = (lane < 32) ? chs[wav][64 + lane] : -INFINITY;
            float mx = fmaxf(v0, v1);
            #pragma unroll
            for (int s = 32; s > 0; s >>= 1) mx = fmaxf(mx, __shfl_xor(mx, s, 64));
            float q0 = v0 / mx;
            size_t base = ((size_t)(b0 + wav) * TT + t) * CC;
            if (q0 > THRV) out[base + lane] = q0;
            if (lane < 32) {
                float q1 = v1 / mx;
                if (q1 > THRV) out[base + 64 + lane] = q1;
            }
            float q52 = __shfl(q0, 52, 64);
            if (!found && q52 == 1.0f) { found = true; len = t + 1; }
        }
        // no barrier needed: two barriers separate these chs reads from the next
        // iteration's chs writes; phase 4 touches no LDS that phase 1 writes.
    }

    // ---- epilogue: replicate stable chars for t in [tex, TT) ----
    if (tex < TT) {
        // chs still holds the stable chars (== chars for every remaining step).
        float v0 = chs[wav][lane];
        float v1 = (lane < 32) ? chs[wav][64 + lane] : -INFINITY;
        float mx = fmaxf(v0, v1);
        #pragma unroll
        for (int s = 32; s > 0; s >>= 1) mx = fmaxf(mx, __shfl_xor(mx, s, 64));
        size_t rowbase = (size_t)(b0 + wav) * TT * CC;
        float q0 = v0 / mx;
        if (q0 > THRV)
            for (int t = tex; t < TT; ++t) out[rowbase + (size_t)t * CC + lane] = q0;
        if (lane < 32) {
            float q1 = v1 / mx;
            if (q1 > THRV)
                for (int t = tex; t < TT; ++t) out[rowbase + (size_t)t * CC + 64 + lane] = q1;
        }
        // lens: if char 52 were the stable argmax it was already found at step
        // tex-1 (identical chars). So `len`/`found` are final as-is.
    }

    if (lane == 0) lens[b0 + wav] = (float)len;
}

extern "C" void kernel_launch(void* const* d_in, const int* in_sizes, int n_in,
                              void* d_out, int out_size, void* d_ws, size_t ws_size,
                              hipStream_t stream)
{
    const float* img = (const float*)d_in[0];
    const float* l1w = (const float*)d_in[1];
    const float* l1b = (const float*)d_in[2];
    const float* wih = (const float*)d_in[3];
    const float* whh = (const float*)d_in[4];
    const float* bih = (const float*)d_in[5];
    const float* bhh = (const float*)d_in[6];
    const float* l2w = (const float*)d_in[7];
    const float* l2b = (const float*)d_in[8];

    float* out  = (float*)d_out;
    float* lens = out + (size_t)2048 * TT * CC;

    // titles is ~99% zeros: clear everything, kernel scatters only survivors.
    hipMemsetAsync(d_out, 0, (size_t)out_size * sizeof(float), stream);

    gru_title<<<dim3(2048 / NB), dim3(512), 0, stream>>>(
        img, l1w, l1b, wih, whh, bih, bhh, l2w, l2b, out, lens);
}